// Round 8
// baseline (413.313 us; speedup 1.0000x reference)
//
#include <hip/hip_runtime.h>
#include <hip/hip_bf16.h>

#define NN   100000
#define HIDD 128
#define NB   782          // ceil(NN/128) buckets of 128 nodes

typedef __attribute__((ext_vector_type(8))) short bf16x8;
typedef __attribute__((ext_vector_type(4))) float f32x4;

// RNE fp32 -> bf16 bits
__device__ __forceinline__ short bf16_rne(float v) {
    unsigned u = __float_as_uint(v);
    unsigned r = (u + 0x7fffu + ((u >> 16) & 1u)) >> 16;
    return (short)r;
}
__device__ __forceinline__ float bf16_to_f32(short b) {
    return __uint_as_float(((unsigned)(unsigned short)b) << 16);
}
__device__ __forceinline__ float2 unpack2(unsigned u) {
    float2 r;
    r.x = __uint_as_float((u & 0xFFFFu) << 16);
    r.y = __uint_as_float(u & 0xFFFF0000u);
    return r;
}
__device__ __forceinline__ unsigned pack2(float a, float b) {
    return ((unsigned)(unsigned short)bf16_rne(a)) |
           (((unsigned)(unsigned short)bf16_rne(b)) << 16);
}

// ---------------------------------------------------------------------------
// Bucketed CSR build. bucket = dst >> 7 (128 nodes per bucket).
// ---------------------------------------------------------------------------
__global__ __launch_bounds__(256)
void bucket_hist(const int* __restrict__ edges, int n_edges,
                 int* __restrict__ bcnt) {
    __shared__ int lh[NB];
    for (int i = threadIdx.x; i < NB; i += 256) lh[i] = 0;
    __syncthreads();
    int stride = gridDim.x * blockDim.x;
    for (int e = blockIdx.x * blockDim.x + threadIdx.x; e < n_edges; e += stride) {
        int d = edges[n_edges + e];
        if ((unsigned)d < NN) atomicAdd(&lh[d >> 7], 1);
    }
    __syncthreads();
    for (int i = threadIdx.x; i < NB; i += 256)
        if (lh[i]) atomicAdd(&bcnt[i], lh[i]);
}

__global__ void scan_bptr(const int* __restrict__ bcnt, int* __restrict__ bptr) {
    __shared__ int lds[1024];
    int t = threadIdx.x;
    lds[t] = (t < NB) ? bcnt[t] : 0;
    __syncthreads();
    for (int off = 1; off < 1024; off <<= 1) {
        int u = (t >= off) ? lds[t - off] : 0;
        __syncthreads();
        lds[t] += u;
        __syncthreads();
    }
    if (t < NB) bptr[t + 1] = lds[t];
    if (t == 0) bptr[0] = 0;
}

// Scatter edges into bucket regions as packed (dst_local<<17 | src).
// Small chunk => 782 blocks => CUs actually busy (r7: 98 blocks = 3.9% occ).
#define SCAT_CHUNK 2048
__global__ __launch_bounds__(256)
void bucket_scatter(const int* __restrict__ edges, int n_edges,
                    const int* __restrict__ bptr, int* __restrict__ bcur,
                    int* __restrict__ bedges) {
    __shared__ int lh[NB];
    __shared__ int lbase[NB];
    int t = threadIdx.x;
    int base = blockIdx.x * SCAT_CHUNK;
    for (int i = t; i < NB; i += 256) lh[i] = 0;
    __syncthreads();
#pragma unroll
    for (int i = 0; i < SCAT_CHUNK / 256; ++i) {
        int e = base + i * 256 + t;
        if (e < n_edges) {
            int d = edges[n_edges + e];
            if ((unsigned)d < NN) atomicAdd(&lh[d >> 7], 1);
        }
    }
    __syncthreads();
    for (int i = t; i < NB; i += 256) {
        int c = lh[i];
        lbase[i] = (c > 0) ? atomicAdd(&bcur[i], c) : 0;
        lh[i] = 0;   // reuse as cursor
    }
    __syncthreads();
#pragma unroll
    for (int i = 0; i < SCAT_CHUNK / 256; ++i) {
        int e = base + i * 256 + t;
        if (e < n_edges) {
            int s = edges[e];
            int d = edges[n_edges + e];
            if ((unsigned)d < NN && (unsigned)s < NN) {
                int b = d >> 7;
                int off = atomicAdd(&lh[b], 1);
                bedges[bptr[b] + lbase[b] + off] = ((d & 127) << 17) | s;
            }
        }
    }
}

// One block per bucket: local count -> scan -> place. Emits row_ptr + col_src.
__global__ __launch_bounds__(256)
void bucket_csr(const int* __restrict__ bedges, const int* __restrict__ bptr,
                int* __restrict__ row_ptr, int* __restrict__ col_src) {
    __shared__ int lcnt[128];
    __shared__ int lexcl[128];
    int b = blockIdx.x;
    int t = threadIdx.x;
    int beg = bptr[b], end = bptr[b + 1];
    if (t < 128) lcnt[t] = 0;
    __syncthreads();
    for (int e = beg + t; e < end; e += 256)
        atomicAdd(&lcnt[bedges[e] >> 17], 1);
    __syncthreads();
    if (t < 128) lexcl[t] = lcnt[t];
    __syncthreads();
    for (int off = 1; off < 128; off <<= 1) {
        int u = (t < 128 && t >= off) ? lexcl[t - off] : 0;
        __syncthreads();
        if (t < 128) lexcl[t] += u;
        __syncthreads();
    }
    int node0 = b << 7;
    if (t < 128) {
        int excl = lexcl[t] - lcnt[t];   // exclusive scan
        int node = node0 + t;
        if (node < NN) row_ptr[node] = beg + excl;
        lexcl[t] = excl;
        lcnt[t] = 0;                     // reuse as cursor
    }
    if (b == NB - 1 && t == 0) row_ptr[NN] = end;
    __syncthreads();
    for (int e = beg + t; e < end; e += 256) {
        int p = bedges[e];
        int dl = p >> 17, src = p & 0x1FFFF;
        int pos = atomicAdd(&lcnt[dl], 1);
        col_src[beg + lexcl[dl] + pos] = src;
    }
}

// ---------------------------------------------------------------------------
// fp32 -> bf16 conversion (x)
// ---------------------------------------------------------------------------
__global__ void to_bf16(const float* __restrict__ in, ushort* __restrict__ out, int n) {
    int i = (blockIdx.x * blockDim.x + threadIdx.x) * 4;
    if (i + 3 >= n) {
        for (int k = i; k < n; ++k) out[k] = (ushort)bf16_rne(in[k]);
        return;
    }
    float4 v = *(const float4*)&in[i];
    unsigned lo = pack2(v.x, v.y), hi = pack2(v.z, v.w);
    *(uint2*)&out[i] = make_uint2(lo, hi);
}

// ---------------------------------------------------------------------------
// Pull-mode mean aggregation on bf16 activations (8-deep MLP unroll).
// ---------------------------------------------------------------------------
__global__ void aggregate128_bf16(const ushort* __restrict__ h16,
                                  const int* __restrict__ row_ptr,
                                  const int* __restrict__ col_src,
                                  ushort* __restrict__ aggr16, int n_nodes) {
    int node = (int)((blockIdx.x * (size_t)blockDim.x + threadIdx.x) >> 6);
    int lane = threadIdx.x & 63;
    if (node >= n_nodes) return;
    int beg = row_ptr[node], end = row_ptr[node + 1];
    float ax = 0.f, ay = 0.f;
    int j = beg;
    for (; j + 8 <= end; j += 8) {
        unsigned u0 = *(const unsigned*)&h16[(size_t)col_src[j + 0] * HIDD + lane * 2];
        unsigned u1 = *(const unsigned*)&h16[(size_t)col_src[j + 1] * HIDD + lane * 2];
        unsigned u2 = *(const unsigned*)&h16[(size_t)col_src[j + 2] * HIDD + lane * 2];
        unsigned u3 = *(const unsigned*)&h16[(size_t)col_src[j + 3] * HIDD + lane * 2];
        unsigned u4 = *(const unsigned*)&h16[(size_t)col_src[j + 4] * HIDD + lane * 2];
        unsigned u5 = *(const unsigned*)&h16[(size_t)col_src[j + 5] * HIDD + lane * 2];
        unsigned u6 = *(const unsigned*)&h16[(size_t)col_src[j + 6] * HIDD + lane * 2];
        unsigned u7 = *(const unsigned*)&h16[(size_t)col_src[j + 7] * HIDD + lane * 2];
        float2 v0 = unpack2(u0), v1 = unpack2(u1), v2 = unpack2(u2), v3 = unpack2(u3);
        float2 v4 = unpack2(u4), v5 = unpack2(u5), v6 = unpack2(u6), v7 = unpack2(u7);
        ax += ((v0.x + v1.x) + (v2.x + v3.x)) + ((v4.x + v5.x) + (v6.x + v7.x));
        ay += ((v0.y + v1.y) + (v2.y + v3.y)) + ((v4.y + v5.y) + (v6.y + v7.y));
    }
    for (; j + 4 <= end; j += 4) {
        unsigned u0 = *(const unsigned*)&h16[(size_t)col_src[j + 0] * HIDD + lane * 2];
        unsigned u1 = *(const unsigned*)&h16[(size_t)col_src[j + 1] * HIDD + lane * 2];
        unsigned u2 = *(const unsigned*)&h16[(size_t)col_src[j + 2] * HIDD + lane * 2];
        unsigned u3 = *(const unsigned*)&h16[(size_t)col_src[j + 3] * HIDD + lane * 2];
        float2 v0 = unpack2(u0), v1 = unpack2(u1), v2 = unpack2(u2), v3 = unpack2(u3);
        ax += (v0.x + v1.x) + (v2.x + v3.x);
        ay += (v0.y + v1.y) + (v2.y + v3.y);
    }
    for (; j < end; ++j) {
        float2 v = unpack2(*(const unsigned*)&h16[(size_t)col_src[j] * HIDD + lane * 2]);
        ax += v.x; ay += v.y;
    }
    float inv = (end > beg) ? 1.0f / (float)(end - beg) : 0.0f;
    *(unsigned*)&aggr16[(size_t)node * HIDD + lane * 2] = pack2(ax * inv, ay * inv);
}

// 16 lanes per node (K=32: 2 bf16 per lane)
__global__ void aggregate32_bf16(const ushort* __restrict__ x16,
                                 const int* __restrict__ row_ptr,
                                 const int* __restrict__ col_src,
                                 ushort* __restrict__ aggr16, int n_nodes) {
    int node = (int)((blockIdx.x * (size_t)blockDim.x + threadIdx.x) >> 4);
    int sl = threadIdx.x & 15;
    if (node >= n_nodes) return;
    int beg = row_ptr[node], end = row_ptr[node + 1];
    float ax = 0.f, ay = 0.f;
    int j = beg;
    for (; j + 8 <= end; j += 8) {
        float2 v0 = unpack2(*(const unsigned*)&x16[(size_t)col_src[j + 0] * 32 + sl * 2]);
        float2 v1 = unpack2(*(const unsigned*)&x16[(size_t)col_src[j + 1] * 32 + sl * 2]);
        float2 v2 = unpack2(*(const unsigned*)&x16[(size_t)col_src[j + 2] * 32 + sl * 2]);
        float2 v3 = unpack2(*(const unsigned*)&x16[(size_t)col_src[j + 3] * 32 + sl * 2]);
        float2 v4 = unpack2(*(const unsigned*)&x16[(size_t)col_src[j + 4] * 32 + sl * 2]);
        float2 v5 = unpack2(*(const unsigned*)&x16[(size_t)col_src[j + 5] * 32 + sl * 2]);
        float2 v6 = unpack2(*(const unsigned*)&x16[(size_t)col_src[j + 6] * 32 + sl * 2]);
        float2 v7 = unpack2(*(const unsigned*)&x16[(size_t)col_src[j + 7] * 32 + sl * 2]);
        ax += ((v0.x + v1.x) + (v2.x + v3.x)) + ((v4.x + v5.x) + (v6.x + v7.x));
        ay += ((v0.y + v1.y) + (v2.y + v3.y)) + ((v4.y + v5.y) + (v6.y + v7.y));
    }
    for (; j + 4 <= end; j += 4) {
        float2 v0 = unpack2(*(const unsigned*)&x16[(size_t)col_src[j + 0] * 32 + sl * 2]);
        float2 v1 = unpack2(*(const unsigned*)&x16[(size_t)col_src[j + 1] * 32 + sl * 2]);
        float2 v2 = unpack2(*(const unsigned*)&x16[(size_t)col_src[j + 2] * 32 + sl * 2]);
        float2 v3 = unpack2(*(const unsigned*)&x16[(size_t)col_src[j + 3] * 32 + sl * 2]);
        ax += (v0.x + v1.x) + (v2.x + v3.x);
        ay += (v0.y + v1.y) + (v2.y + v3.y);
    }
    for (; j < end; ++j) {
        float2 v = unpack2(*(const unsigned*)&x16[(size_t)col_src[j] * 32 + sl * 2]);
        ax += v.x; ay += v.y;
    }
    float inv = (end > beg) ? 1.0f / (float)(end - beg) : 0.0f;
    *(unsigned*)&aggr16[(size_t)node * 32 + sl * 2] = pack2(ax * inv, ay * inv);
}

// ---------------------------------------------------------------------------
// Weight pre-split: fp32 -> (hi, lo) bf16 planes, all 6 conv matrices.
// ---------------------------------------------------------------------------
__global__ void split_weights(const float* __restrict__ W1l, const float* __restrict__ W1r,
                              const float* __restrict__ W2l, const float* __restrict__ W2r,
                              const float* __restrict__ W3l, const float* __restrict__ W3r,
                              short* __restrict__ whi, short* __restrict__ wlo) {
    int i = blockIdx.x * blockDim.x + threadIdx.x;
    if (i >= 73728) return;
    const float* src; int off;
    if (i < 4096)       { src = W1l; off = 0; }
    else if (i < 8192)  { src = W1r; off = 4096; }
    else if (i < 24576) { src = W2l; off = 8192; }
    else if (i < 40960) { src = W2r; off = 24576; }
    else if (i < 57344) { src = W3l; off = 40960; }
    else                { src = W3r; off = 57344; }
    float v = src[i - off];
    short h = bf16_rne(v);
    float l = v - bf16_to_f32(h);
    whi[i] = h;
    wlo[i] = bf16_rne(l);
}

// ---------------------------------------------------------------------------
// Row-streaming MFMA dual GEMM, W pinned in registers — v3.
// Wave owns a 16-col strip => W regs = 2op*NCH*2plane = 16 bf16x8 (64 VGPR),
// total ~115 VGPR => compiler keeps W resident at 4 waves/SIMD (r7 failed
// at ~220 need: compiler demoted W to reloads, VGPR=80, latency-bound).
// Block = 4 waves = 64 cols; blockIdx&1 = col half; grid-stride over 16-row
// tiles (NN = 6250*16 exact). Per tile: 2*NCH A loads + 4*NCH MFMA.
// MEAN: per-wave column sums in regs; shuffle-reduce + atomics at end.
// ---------------------------------------------------------------------------
template <int KA, bool RELU, bool MEAN>
__global__ __launch_bounds__(256)
void gemm_mfma(const ushort* __restrict__ inA, const ushort* __restrict__ inB,
               const short* __restrict__ WAhi, const short* __restrict__ WAlo,
               const short* __restrict__ WBhi, const short* __restrict__ WBlo,
               const float* __restrict__ bias,
               ushort* __restrict__ out, float* __restrict__ gsum) {
    constexpr int NCH = KA / 32;        // k-chunks
    constexpr int NT  = NN / 16;        // 6250 row tiles
    const int t = threadIdx.x;
    const int wave = t >> 6, lane = t & 63;
    const int lrow = lane & 15;
    const int lk8  = (lane >> 4) * 8;
    const int half = blockIdx.x & 1;
    const int o0   = half * 64 + wave * 16;   // wave's 16-col strip
    const int rg   = (lane >> 4) * 4;         // C row-group base

    // ---- W fragments pinned in registers (whole kernel) ----
    bf16x8 w[2][NCH][2];                // [op][chunk][plane]
#pragma unroll
    for (int op = 0; op < 2; ++op) {
        const short* __restrict__ Whi = op ? WBhi : WAhi;
        const short* __restrict__ Wlo = op ? WBlo : WAlo;
#pragma unroll
        for (int ch = 0; ch < NCH; ++ch) {
            size_t wb = (size_t)(o0 + lrow) * KA + ch * 32 + lk8;
            w[op][ch][0] = *(const bf16x8*)&Whi[wb];
            w[op][ch][1] = *(const bf16x8*)&Wlo[wb];
        }
    }
    const float bv = MEAN ? 0.f : bias[o0 + lrow];
    float csum = 0.f;

    const int step = gridDim.x >> 1;
    for (int rt = blockIdx.x >> 1; rt < NT; rt += step) {
        // ---- all A loads issued up front (independent) ----
        bf16x8 a[2][NCH];
#pragma unroll
        for (int op = 0; op < 2; ++op) {
            const ushort* __restrict__ in = op ? inB : inA;
            const ushort* ab = in + (size_t)(rt * 16 + lrow) * KA + lk8;
#pragma unroll
            for (int ch = 0; ch < NCH; ++ch) a[op][ch] = *(const bf16x8*)(ab + ch * 32);
        }
        f32x4 acc = (f32x4){0.f, 0.f, 0.f, 0.f};
#pragma unroll
        for (int op = 0; op < 2; ++op)
#pragma unroll
            for (int ch = 0; ch < NCH; ++ch) {
                acc = __builtin_amdgcn_mfma_f32_16x16x32_bf16(a[op][ch], w[op][ch][0], acc, 0, 0, 0);
                acc = __builtin_amdgcn_mfma_f32_16x16x32_bf16(a[op][ch], w[op][ch][1], acc, 0, 0, 0);
            }
        if (!MEAN) {
            const int o = o0 + lrow;
#pragma unroll
            for (int r = 0; r < 4; ++r) {
                float v = acc[r] + bv;
                if (RELU) v = fmaxf(v, 0.f);
                out[(size_t)(rt * 16 + rg + r) * HIDD + o] = (ushort)bf16_rne(v);
            }
        } else {
            csum += (acc[0] + acc[1]) + (acc[2] + acc[3]);
        }
    }

    if (MEAN) {
        float s = csum;
        s += __shfl_xor(s, 16);
        s += __shfl_xor(s, 32);
        if (lane < 16) atomicAdd(&gsum[o0 + lane], s);
    }
}

// ---------------------------------------------------------------------------
// Heads: g = gsum/N + b3; logits = relu(g@Pw1.T+Pb1)@Pw2.T+Pb2; value likewise.
// ---------------------------------------------------------------------------
__global__ void heads_kernel(const float* __restrict__ gsum,
                             const float* __restrict__ b3,
                             const float* __restrict__ Pw1, const float* __restrict__ Pb1,
                             const float* __restrict__ Pw2, const float* __restrict__ Pb2,
                             const float* __restrict__ Vw1, const float* __restrict__ Vb1,
                             const float* __restrict__ Vw2, const float* __restrict__ Vb2,
                             float* __restrict__ out, float inv_n) {
    __shared__ float g[128], a1[128], v1[128];
    int t = threadIdx.x;
    if (t < 128) g[t] = gsum[t] * inv_n + b3[t];
    __syncthreads();
    if (t < 128) {
        float s = Pb1[t];
        for (int f = 0; f < 128; ++f) s = fmaf(Pw1[t * 128 + f], g[f], s);
        a1[t] = fmaxf(s, 0.f);
    } else {
        int o = t - 128;
        float s = Vb1[o];
        for (int f = 0; f < 128; ++f) s = fmaf(Vw1[o * 128 + f], g[f], s);
        v1[o] = fmaxf(s, 0.f);
    }
    __syncthreads();
    if (t < 6) {
        float s = Pb2[t];
        for (int f = 0; f < 128; ++f) s = fmaf(Pw2[t * 128 + f], a1[f], s);
        out[t] = s;
    }
    if (t == 6) {
        float s = Vb2[0];
        for (int f = 0; f < 128; ++f) s = fmaf(Vw2[f], v1[f], s);
        out[6] = s;
    }
}

// ---------------------------------------------------------------------------
extern "C" void kernel_launch(void* const* d_in, const int* in_sizes, int n_in,
                              void* d_out, int out_size, void* d_ws, size_t ws_size,
                              hipStream_t stream) {
    const float* x    = (const float*)d_in[0];
    const int*   edges = (const int*)d_in[1];
    const float* W1l = (const float*)d_in[2];
    const float* b1  = (const float*)d_in[3];
    const float* W1r = (const float*)d_in[4];
    const float* W2l = (const float*)d_in[5];
    const float* b2  = (const float*)d_in[6];
    const float* W2r = (const float*)d_in[7];
    const float* W3l = (const float*)d_in[8];
    const float* b3  = (const float*)d_in[9];
    const float* W3r = (const float*)d_in[10];
    const float* Pw1 = (const float*)d_in[11];
    const float* Pb1 = (const float*)d_in[12];
    const float* Pw2 = (const float*)d_in[13];
    const float* Pb2 = (const float*)d_in[14];
    const float* Vw1 = (const float*)d_in[15];
    const float* Vb1 = (const float*)d_in[16];
    const float* Vw2 = (const float*)d_in[17];
    const float* Vb2 = (const float*)d_in[18];
    float* outp = (float*)d_out;

    const int E = in_sizes[1] / 2;

    // ---- workspace layout (int offsets, regions 256B-aligned) ----
    int*   ws_i = (int*)d_ws;
    float* ws_f = (float*)d_ws;
    size_t o_bcnt = 0;                 // NB ints   (zeroed)
    size_t o_bcur = 832;               // NB ints   (zeroed)
    size_t o_gsum = 1664;              // 128 f32   (zeroed)
    size_t o_bptr = 1792;              // NB+1
    size_t o_rowp = 2624;              // NN+1
    size_t o_bed  = 102656;            // E packed bucket edges
    size_t o_col  = o_bed + (size_t)E;           // E
    size_t o_whi  = ((o_col + (size_t)E + 63) / 64) * 64;  // 73728 shorts = 36864 ints
    size_t o_wlo  = o_whi + 36864;
    size_t o_x16  = o_wlo + 36864;               // NN*32 bf16 = NN*16 ints
    size_t o_aggr = o_x16 + (size_t)NN * 16;     // NN*128 bf16 = NN*64 ints
    size_t o_hA   = o_aggr + (size_t)NN * 64;
    size_t o_hB   = o_hA + (size_t)NN * 64;

    int*    bcnt    = ws_i + o_bcnt;
    int*    bcur    = ws_i + o_bcur;
    float*  gsum    = ws_f + o_gsum;
    int*    bptr    = ws_i + o_bptr;
    int*    row_ptr = ws_i + o_rowp;
    int*    bedges  = ws_i + o_bed;
    int*    col_src = ws_i + o_col;
    short*  whi     = (short*)(ws_i + o_whi);
    short*  wlo     = (short*)(ws_i + o_wlo);
    ushort* x16     = (ushort*)(ws_i + o_x16);
    ushort* aggr    = (ushort*)(ws_i + o_aggr);
    ushort* hA      = (ushort*)(ws_i + o_hA);
    ushort* hB      = (ushort*)(ws_i + o_hB);

    short* W1l_hi = whi + 0;     short* W1l_lo = wlo + 0;
    short* W1r_hi = whi + 4096;  short* W1r_lo = wlo + 4096;
    short* W2l_hi = whi + 8192;  short* W2l_lo = wlo + 8192;
    short* W2r_hi = whi + 24576; short* W2r_lo = wlo + 24576;
    short* W3l_hi = whi + 40960; short* W3l_lo = wlo + 40960;
    short* W3r_hi = whi + 57344; short* W3r_lo = wlo + 57344;

    // zero bcnt, bcur, gsum
    hipMemsetAsync(d_ws, 0, 1792 * sizeof(int), stream);

    const int TB = 256;
    dim3 blk(TB);

    // independent prep
    to_bf16<<<(NN * 32 / 4 + TB - 1) / TB, blk, 0, stream>>>(x, x16, NN * 32);
    split_weights<<<(73728 + TB - 1) / TB, blk, 0, stream>>>(
        W1l, W1r, W2l, W2r, W3l, W3r, whi, wlo);

    // bucketed CSR build
    bucket_hist<<<256, blk, 0, stream>>>(edges, E, bcnt);
    scan_bptr<<<1, 1024, 0, stream>>>(bcnt, bptr);
    bucket_scatter<<<(E + SCAT_CHUNK - 1) / SCAT_CHUNK, blk, 0, stream>>>(
        edges, E, bptr, bcur, bedges);
    bucket_csr<<<NB, blk, 0, stream>>>(bedges, bptr, row_ptr, col_src);

    dim3 grid_a32((size_t)NN * 16 / TB);   // 6250
    dim3 grid_a128((size_t)NN * 64 / TB);  // 25000
    dim3 grid_g(4096);                     // 2048 blocks per col-half

    // Layer 1 (K=32, relu)
    aggregate32_bf16<<<grid_a32, blk, 0, stream>>>(x16, row_ptr, col_src, aggr, NN);
    gemm_mfma<32, true, false><<<grid_g, blk, 0, stream>>>(
        aggr, x16, W1l_hi, W1l_lo, W1r_hi, W1r_lo, b1, hA, nullptr);

    // Layer 2 (K=128, relu)
    aggregate128_bf16<<<grid_a128, blk, 0, stream>>>(hA, row_ptr, col_src, aggr, NN);
    gemm_mfma<128, true, false><<<grid_g, blk, 0, stream>>>(
        aggr, hA, W2l_hi, W2l_lo, W2r_hi, W2r_lo, b2, hB, nullptr);

    // Layer 3 (K=128, fused column-mean into gsum)
    aggregate128_bf16<<<grid_a128, blk, 0, stream>>>(hB, row_ptr, col_src, aggr, NN);
    gemm_mfma<128, false, true><<<grid_g, blk, 0, stream>>>(
        aggr, hB, W3l_hi, W3l_lo, W3r_hi, W3r_lo, b3, nullptr, gsum);

    // Heads (b3 folded into global mean here)
    heads_kernel<<<1, 256, 0, stream>>>(gsum, b3, Pw1, Pb1, Pw2, Pb2,
                                        Vw1, Vb1, Vw2, Vb2, outp,
                                        1.0f / (float)NN);
}

// Round 9
// 357.529 us; speedup vs baseline: 1.1560x; 1.1560x over previous
//
#include <hip/hip_runtime.h>
#include <hip/hip_bf16.h>

#define NN   100000
#define HIDD 128
#define NB   782          // ceil(NN/128) buckets of 128 nodes

typedef __attribute__((ext_vector_type(8))) short bf16x8;
typedef __attribute__((ext_vector_type(4))) float f32x4;

// RNE fp32 -> bf16 bits
__device__ __forceinline__ short bf16_rne(float v) {
    unsigned u = __float_as_uint(v);
    unsigned r = (u + 0x7fffu + ((u >> 16) & 1u)) >> 16;
    return (short)r;
}
__device__ __forceinline__ float bf16_to_f32(short b) {
    return __uint_as_float(((unsigned)(unsigned short)b) << 16);
}
__device__ __forceinline__ float2 unpack2(unsigned u) {
    float2 r;
    r.x = __uint_as_float((u & 0xFFFFu) << 16);
    r.y = __uint_as_float(u & 0xFFFF0000u);
    return r;
}
__device__ __forceinline__ unsigned pack2(float a, float b) {
    return ((unsigned)(unsigned short)bf16_rne(a)) |
           (((unsigned)(unsigned short)bf16_rne(b)) << 16);
}

// ---------------------------------------------------------------------------
// Bucketed CSR build. bucket = dst >> 7 (128 nodes per bucket).
// ---------------------------------------------------------------------------
__global__ __launch_bounds__(256)
void bucket_hist(const int* __restrict__ edges, int n_edges,
                 int* __restrict__ bcnt) {
    __shared__ int lh[NB];
    for (int i = threadIdx.x; i < NB; i += 256) lh[i] = 0;
    __syncthreads();
    int stride = gridDim.x * blockDim.x;
    for (int e = blockIdx.x * blockDim.x + threadIdx.x; e < n_edges; e += stride) {
        int d = edges[n_edges + e];
        if ((unsigned)d < NN) atomicAdd(&lh[d >> 7], 1);
    }
    __syncthreads();
    for (int i = threadIdx.x; i < NB; i += 256)
        if (lh[i]) atomicAdd(&bcnt[i], lh[i]);
}

__global__ void scan_bptr(const int* __restrict__ bcnt, int* __restrict__ bptr) {
    __shared__ int lds[1024];
    int t = threadIdx.x;
    lds[t] = (t < NB) ? bcnt[t] : 0;
    __syncthreads();
    for (int off = 1; off < 1024; off <<= 1) {
        int u = (t >= off) ? lds[t - off] : 0;
        __syncthreads();
        lds[t] += u;
        __syncthreads();
    }
    if (t < NB) bptr[t + 1] = lds[t];
    if (t == 0) bptr[0] = 0;
}

// Scatter edges into bucket regions as packed (dst_local<<17 | src).
#define SCAT_CHUNK 2048
__global__ __launch_bounds__(256)
void bucket_scatter(const int* __restrict__ edges, int n_edges,
                    const int* __restrict__ bptr, int* __restrict__ bcur,
                    int* __restrict__ bedges) {
    __shared__ int lh[NB];
    __shared__ int lbase[NB];
    int t = threadIdx.x;
    int base = blockIdx.x * SCAT_CHUNK;
    for (int i = t; i < NB; i += 256) lh[i] = 0;
    __syncthreads();
#pragma unroll
    for (int i = 0; i < SCAT_CHUNK / 256; ++i) {
        int e = base + i * 256 + t;
        if (e < n_edges) {
            int d = edges[n_edges + e];
            if ((unsigned)d < NN) atomicAdd(&lh[d >> 7], 1);
        }
    }
    __syncthreads();
    for (int i = t; i < NB; i += 256) {
        int c = lh[i];
        lbase[i] = (c > 0) ? atomicAdd(&bcur[i], c) : 0;
        lh[i] = 0;   // reuse as cursor
    }
    __syncthreads();
#pragma unroll
    for (int i = 0; i < SCAT_CHUNK / 256; ++i) {
        int e = base + i * 256 + t;
        if (e < n_edges) {
            int s = edges[e];
            int d = edges[n_edges + e];
            if ((unsigned)d < NN && (unsigned)s < NN) {
                int b = d >> 7;
                int off = atomicAdd(&lh[b], 1);
                bedges[bptr[b] + lbase[b] + off] = ((d & 127) << 17) | s;
            }
        }
    }
}

// One block per bucket: local count -> scan -> place. Emits row_ptr + col_src.
__global__ __launch_bounds__(256)
void bucket_csr(const int* __restrict__ bedges, const int* __restrict__ bptr,
                int* __restrict__ row_ptr, int* __restrict__ col_src) {
    __shared__ int lcnt[128];
    __shared__ int lexcl[128];
    int b = blockIdx.x;
    int t = threadIdx.x;
    int beg = bptr[b], end = bptr[b + 1];
    if (t < 128) lcnt[t] = 0;
    __syncthreads();
    for (int e = beg + t; e < end; e += 256)
        atomicAdd(&lcnt[bedges[e] >> 17], 1);
    __syncthreads();
    if (t < 128) lexcl[t] = lcnt[t];
    __syncthreads();
    for (int off = 1; off < 128; off <<= 1) {
        int u = (t < 128 && t >= off) ? lexcl[t - off] : 0;
        __syncthreads();
        if (t < 128) lexcl[t] += u;
        __syncthreads();
    }
    int node0 = b << 7;
    if (t < 128) {
        int excl = lexcl[t] - lcnt[t];   // exclusive scan
        int node = node0 + t;
        if (node < NN) row_ptr[node] = beg + excl;
        lexcl[t] = excl;
        lcnt[t] = 0;                     // reuse as cursor
    }
    if (b == NB - 1 && t == 0) row_ptr[NN] = end;
    __syncthreads();
    for (int e = beg + t; e < end; e += 256) {
        int p = bedges[e];
        int dl = p >> 17, src = p & 0x1FFFF;
        int pos = atomicAdd(&lcnt[dl], 1);
        col_src[beg + lexcl[dl] + pos] = src;
    }
}

// ---------------------------------------------------------------------------
// fp32 -> bf16 conversion (x)
// ---------------------------------------------------------------------------
__global__ void to_bf16(const float* __restrict__ in, ushort* __restrict__ out, int n) {
    int i = (blockIdx.x * blockDim.x + threadIdx.x) * 4;
    if (i + 3 >= n) {
        for (int k = i; k < n; ++k) out[k] = (ushort)bf16_rne(in[k]);
        return;
    }
    float4 v = *(const float4*)&in[i];
    unsigned lo = pack2(v.x, v.y), hi = pack2(v.z, v.w);
    *(uint2*)&out[i] = make_uint2(lo, hi);
}

// ---------------------------------------------------------------------------
// Pull-mode mean aggregation on bf16 activations (8-deep MLP unroll).
// ---------------------------------------------------------------------------
__global__ void aggregate128_bf16(const ushort* __restrict__ h16,
                                  const int* __restrict__ row_ptr,
                                  const int* __restrict__ col_src,
                                  ushort* __restrict__ aggr16, int n_nodes) {
    int node = (int)((blockIdx.x * (size_t)blockDim.x + threadIdx.x) >> 6);
    int lane = threadIdx.x & 63;
    if (node >= n_nodes) return;
    int beg = row_ptr[node], end = row_ptr[node + 1];
    float ax = 0.f, ay = 0.f;
    int j = beg;
    for (; j + 8 <= end; j += 8) {
        unsigned u0 = *(const unsigned*)&h16[(size_t)col_src[j + 0] * HIDD + lane * 2];
        unsigned u1 = *(const unsigned*)&h16[(size_t)col_src[j + 1] * HIDD + lane * 2];
        unsigned u2 = *(const unsigned*)&h16[(size_t)col_src[j + 2] * HIDD + lane * 2];
        unsigned u3 = *(const unsigned*)&h16[(size_t)col_src[j + 3] * HIDD + lane * 2];
        unsigned u4 = *(const unsigned*)&h16[(size_t)col_src[j + 4] * HIDD + lane * 2];
        unsigned u5 = *(const unsigned*)&h16[(size_t)col_src[j + 5] * HIDD + lane * 2];
        unsigned u6 = *(const unsigned*)&h16[(size_t)col_src[j + 6] * HIDD + lane * 2];
        unsigned u7 = *(const unsigned*)&h16[(size_t)col_src[j + 7] * HIDD + lane * 2];
        float2 v0 = unpack2(u0), v1 = unpack2(u1), v2 = unpack2(u2), v3 = unpack2(u3);
        float2 v4 = unpack2(u4), v5 = unpack2(u5), v6 = unpack2(u6), v7 = unpack2(u7);
        ax += ((v0.x + v1.x) + (v2.x + v3.x)) + ((v4.x + v5.x) + (v6.x + v7.x));
        ay += ((v0.y + v1.y) + (v2.y + v3.y)) + ((v4.y + v5.y) + (v6.y + v7.y));
    }
    for (; j + 4 <= end; j += 4) {
        unsigned u0 = *(const unsigned*)&h16[(size_t)col_src[j + 0] * HIDD + lane * 2];
        unsigned u1 = *(const unsigned*)&h16[(size_t)col_src[j + 1] * HIDD + lane * 2];
        unsigned u2 = *(const unsigned*)&h16[(size_t)col_src[j + 2] * HIDD + lane * 2];
        unsigned u3 = *(const unsigned*)&h16[(size_t)col_src[j + 3] * HIDD + lane * 2];
        float2 v0 = unpack2(u0), v1 = unpack2(u1), v2 = unpack2(u2), v3 = unpack2(u3);
        ax += (v0.x + v1.x) + (v2.x + v3.x);
        ay += (v0.y + v1.y) + (v2.y + v3.y);
    }
    for (; j < end; ++j) {
        float2 v = unpack2(*(const unsigned*)&h16[(size_t)col_src[j] * HIDD + lane * 2]);
        ax += v.x; ay += v.y;
    }
    float inv = (end > beg) ? 1.0f / (float)(end - beg) : 0.0f;
    *(unsigned*)&aggr16[(size_t)node * HIDD + lane * 2] = pack2(ax * inv, ay * inv);
}

// 16 lanes per node (K=32: 2 bf16 per lane)
__global__ void aggregate32_bf16(const ushort* __restrict__ x16,
                                 const int* __restrict__ row_ptr,
                                 const int* __restrict__ col_src,
                                 ushort* __restrict__ aggr16, int n_nodes) {
    int node = (int)((blockIdx.x * (size_t)blockDim.x + threadIdx.x) >> 4);
    int sl = threadIdx.x & 15;
    if (node >= n_nodes) return;
    int beg = row_ptr[node], end = row_ptr[node + 1];
    float ax = 0.f, ay = 0.f;
    int j = beg;
    for (; j + 8 <= end; j += 8) {
        float2 v0 = unpack2(*(const unsigned*)&x16[(size_t)col_src[j + 0] * 32 + sl * 2]);
        float2 v1 = unpack2(*(const unsigned*)&x16[(size_t)col_src[j + 1] * 32 + sl * 2]);
        float2 v2 = unpack2(*(const unsigned*)&x16[(size_t)col_src[j + 2] * 32 + sl * 2]);
        float2 v3 = unpack2(*(const unsigned*)&x16[(size_t)col_src[j + 3] * 32 + sl * 2]);
        float2 v4 = unpack2(*(const unsigned*)&x16[(size_t)col_src[j + 4] * 32 + sl * 2]);
        float2 v5 = unpack2(*(const unsigned*)&x16[(size_t)col_src[j + 5] * 32 + sl * 2]);
        float2 v6 = unpack2(*(const unsigned*)&x16[(size_t)col_src[j + 6] * 32 + sl * 2]);
        float2 v7 = unpack2(*(const unsigned*)&x16[(size_t)col_src[j + 7] * 32 + sl * 2]);
        ax += ((v0.x + v1.x) + (v2.x + v3.x)) + ((v4.x + v5.x) + (v6.x + v7.x));
        ay += ((v0.y + v1.y) + (v2.y + v3.y)) + ((v4.y + v5.y) + (v6.y + v7.y));
    }
    for (; j + 4 <= end; j += 4) {
        float2 v0 = unpack2(*(const unsigned*)&x16[(size_t)col_src[j + 0] * 32 + sl * 2]);
        float2 v1 = unpack2(*(const unsigned*)&x16[(size_t)col_src[j + 1] * 32 + sl * 2]);
        float2 v2 = unpack2(*(const unsigned*)&x16[(size_t)col_src[j + 2] * 32 + sl * 2]);
        float2 v3 = unpack2(*(const unsigned*)&x16[(size_t)col_src[j + 3] * 32 + sl * 2]);
        ax += (v0.x + v1.x) + (v2.x + v3.x);
        ay += (v0.y + v1.y) + (v2.y + v3.y);
    }
    for (; j < end; ++j) {
        float2 v = unpack2(*(const unsigned*)&x16[(size_t)col_src[j] * 32 + sl * 2]);
        ax += v.x; ay += v.y;
    }
    float inv = (end > beg) ? 1.0f / (float)(end - beg) : 0.0f;
    *(unsigned*)&aggr16[(size_t)node * 32 + sl * 2] = pack2(ax * inv, ay * inv);
}

// ---------------------------------------------------------------------------
// Weight pre-split: fp32 -> (hi, lo) bf16 planes, all 6 conv matrices.
// ---------------------------------------------------------------------------
__global__ void split_weights(const float* __restrict__ W1l, const float* __restrict__ W1r,
                              const float* __restrict__ W2l, const float* __restrict__ W2r,
                              const float* __restrict__ W3l, const float* __restrict__ W3r,
                              short* __restrict__ whi, short* __restrict__ wlo) {
    int i = blockIdx.x * blockDim.x + threadIdx.x;
    if (i >= 73728) return;
    const float* src; int off;
    if (i < 4096)       { src = W1l; off = 0; }
    else if (i < 8192)  { src = W1r; off = 4096; }
    else if (i < 24576) { src = W2l; off = 8192; }
    else if (i < 40960) { src = W2r; off = 24576; }
    else if (i < 57344) { src = W3l; off = 40960; }
    else                { src = W3r; off = 57344; }
    float v = src[i - off];
    short h = bf16_rne(v);
    float l = v - bf16_to_f32(h);
    whi[i] = h;
    wlo[i] = bf16_rne(l);
}

// ---------------------------------------------------------------------------
// LDS-staged MFMA dual GEMM (classic §5 structure; r6-r8 register-pinning
// failed: compiler rematerializes loop-invariant W loads, latency-bound).
// Block = 256 thr = 4 waves, covers a 64-col half (blockIdx&1).
// W-half (hi+lo, both ops) staged ONCE into 64KB LDS with XOR chunk swizzle
// (koff ^ (col&3), applied on write AND read -> ~2 lanes/bank, conflict-free).
// Wave owns a 16-col strip; per iteration processes 32 rows (2 sub-tiles):
// 16 A global loads (all 4 waves same rows -> L1 broadcast), 16 ds_read_b128,
// 32 MFMA. 100000 = 3125*32 exact. Grid-stride over row tiles.
// MEAN: per-lane column sums in regs; shuffle-reduce + atomics at end.
// ---------------------------------------------------------------------------
template <int KA, bool RELU, bool MEAN>
__global__ __launch_bounds__(256, 2)
void gemm_lds(const ushort* __restrict__ inA, const ushort* __restrict__ inB,
              const short* __restrict__ WAhi, const short* __restrict__ WAlo,
              const short* __restrict__ WBhi, const short* __restrict__ WBlo,
              const float* __restrict__ bias,
              ushort* __restrict__ out, float* __restrict__ gsum) {
    constexpr int NCH   = KA / 32;     // k-chunks
    constexpr int NFRAG = 4 * NCH;     // W frags per 16-col strip (2op x NCH x 2pl)
    constexpr int NTILE = NN / 32;     // 3125 row tiles, exact
    __shared__ ushort sW[8192 * NCH];  // 16KB * NCH (64KB at KA=128)

    const int t = threadIdx.x;
    const int wave = t >> 6, lane = t & 63;
    const int lcol = lane & 15;        // B col within strip / A row within tile
    const int koff = lane >> 4;        // which 16B k-chunk of the fragment
    const int half = blockIdx.x & 1;
    const int o0 = half * 64 + wave * 16;

    // ---- cooperative W staging into LDS (swizzled) ----
    for (int i = t; i < 1024 * NCH; i += 256) {
        int tile = i >> 6;             // [0, 16*NCH): (strip, frag)
        int w2 = i & 63;
        int c  = w2 >> 2;              // col 0..15
        int kf = w2 & 3;               // chunk 0..3
        int ws = tile / NFRAG;
        int f  = tile % NFRAG;
        int op = f / (NCH * 2);
        int rem = f % (NCH * 2);
        int ch = rem >> 1;
        int pl = rem & 1;
        const short* Wp = op ? (pl ? WBlo : WBhi) : (pl ? WAlo : WAhi);
        int cg = half * 64 + ws * 16 + c;
        bf16x8 v = *(const bf16x8*)&Wp[(size_t)cg * KA + ch * 32 + kf * 8];
        *(bf16x8*)&sW[ws * (2048 * NCH) + f * 512 + c * 32 + ((kf ^ (c & 3)) * 8)] = v;
    }
    __syncthreads();

    const int wbase = wave * (2048 * NCH) + lcol * 32 + ((koff ^ (lcol & 3)) * 8);
    const int lk8 = koff * 8;
    const float bv = MEAN ? 0.f : bias[o0 + lcol];
    const int rg = koff * 4;           // C row-group base
    float csum = 0.f;

    for (int rt = blockIdx.x >> 1; rt < NTILE; rt += (gridDim.x >> 1)) {
        const int r0 = rt * 32;
        // ---- A loads, all issued up front (independent) ----
        bf16x8 a0[2][NCH], a1[2][NCH];
#pragma unroll
        for (int op = 0; op < 2; ++op) {
            const ushort* __restrict__ in = op ? inB : inA;
            const ushort* p0 = in + (size_t)(r0 + lcol) * KA + lk8;
            const ushort* p1 = in + (size_t)(r0 + 16 + lcol) * KA + lk8;
#pragma unroll
            for (int ch = 0; ch < NCH; ++ch) {
                a0[op][ch] = *(const bf16x8*)(p0 + ch * 32);
                a1[op][ch] = *(const bf16x8*)(p1 + ch * 32);
            }
        }
        f32x4 acc0 = (f32x4){0.f, 0.f, 0.f, 0.f};
        f32x4 acc1 = (f32x4){0.f, 0.f, 0.f, 0.f};
#pragma unroll
        for (int op = 0; op < 2; ++op)
#pragma unroll
            for (int ch = 0; ch < NCH; ++ch)
#pragma unroll
                for (int pl = 0; pl < 2; ++pl) {
                    int f = (op * NCH + ch) * 2 + pl;
                    bf16x8 wf = *(const bf16x8*)&sW[wbase + f * 512];
                    acc0 = __builtin_amdgcn_mfma_f32_16x16x32_bf16(a0[op][ch], wf, acc0, 0, 0, 0);
                    acc1 = __builtin_amdgcn_mfma_f32_16x16x32_bf16(a1[op][ch], wf, acc1, 0, 0, 0);
                }
        if (!MEAN) {
            const int o = o0 + lcol;
#pragma unroll
            for (int r = 0; r < 4; ++r) {
                float v0 = acc0[r] + bv;
                if (RELU) v0 = fmaxf(v0, 0.f);
                out[(size_t)(r0 + rg + r) * HIDD + o] = (ushort)bf16_rne(v0);
                float v1 = acc1[r] + bv;
                if (RELU) v1 = fmaxf(v1, 0.f);
                out[(size_t)(r0 + 16 + rg + r) * HIDD + o] = (ushort)bf16_rne(v1);
            }
        } else {
            csum += ((acc0[0] + acc0[1]) + (acc0[2] + acc0[3]))
                  + ((acc1[0] + acc1[1]) + (acc1[2] + acc1[3]));
        }
    }

    if (MEAN) {
        float s = csum;
        s += __shfl_xor(s, 16);
        s += __shfl_xor(s, 32);
        if (lane < 16) atomicAdd(&gsum[o0 + lane], s);
    }
}

// ---------------------------------------------------------------------------
// Heads: g = gsum/N + b3; logits = relu(g@Pw1.T+Pb1)@Pw2.T+Pb2; value likewise.
// ---------------------------------------------------------------------------
__global__ void heads_kernel(const float* __restrict__ gsum,
                             const float* __restrict__ b3,
                             const float* __restrict__ Pw1, const float* __restrict__ Pb1,
                             const float* __restrict__ Pw2, const float* __restrict__ Pb2,
                             const float* __restrict__ Vw1, const float* __restrict__ Vb1,
                             const float* __restrict__ Vw2, const float* __restrict__ Vb2,
                             float* __restrict__ out, float inv_n) {
    __shared__ float g[128], a1[128], v1[128];
    int t = threadIdx.x;
    if (t < 128) g[t] = gsum[t] * inv_n + b3[t];
    __syncthreads();
    if (t < 128) {
        float s = Pb1[t];
        for (int f = 0; f < 128; ++f) s = fmaf(Pw1[t * 128 + f], g[f], s);
        a1[t] = fmaxf(s, 0.f);
    } else {
        int o = t - 128;
        float s = Vb1[o];
        for (int f = 0; f < 128; ++f) s = fmaf(Vw1[o * 128 + f], g[f], s);
        v1[o] = fmaxf(s, 0.f);
    }
    __syncthreads();
    if (t < 6) {
        float s = Pb2[t];
        for (int f = 0; f < 128; ++f) s = fmaf(Pw2[t * 128 + f], a1[f], s);
        out[t] = s;
    }
    if (t == 6) {
        float s = Vb2[0];
        for (int f = 0; f < 128; ++f) s = fmaf(Vw2[f], v1[f], s);
        out[6] = s;
    }
}

// ---------------------------------------------------------------------------
extern "C" void kernel_launch(void* const* d_in, const int* in_sizes, int n_in,
                              void* d_out, int out_size, void* d_ws, size_t ws_size,
                              hipStream_t stream) {
    const float* x    = (const float*)d_in[0];
    const int*   edges = (const int*)d_in[1];
    const float* W1l = (const float*)d_in[2];
    const float* b1  = (const float*)d_in[3];
    const float* W1r = (const float*)d_in[4];
    const float* W2l = (const float*)d_in[5];
    const float* b2  = (const float*)d_in[6];
    const float* W2r = (const float*)d_in[7];
    const float* W3l = (const float*)d_in[8];
    const float* b3  = (const float*)d_in[9];
    const float* W3r = (const float*)d_in[10];
    const float* Pw1 = (const float*)d_in[11];
    const float* Pb1 = (const float*)d_in[12];
    const float* Pw2 = (const float*)d_in[13];
    const float* Pb2 = (const float*)d_in[14];
    const float* Vw1 = (const float*)d_in[15];
    const float* Vb1 = (const float*)d_in[16];
    const float* Vw2 = (const float*)d_in[17];
    const float* Vb2 = (const float*)d_in[18];
    float* outp = (float*)d_out;

    const int E = in_sizes[1] / 2;

    // ---- workspace layout (int offsets, regions 256B-aligned) ----
    int*   ws_i = (int*)d_ws;
    float* ws_f = (float*)d_ws;
    size_t o_bcnt = 0;                 // NB ints   (zeroed)
    size_t o_bcur = 832;               // NB ints   (zeroed)
    size_t o_gsum = 1664;              // 128 f32   (zeroed)
    size_t o_bptr = 1792;              // NB+1
    size_t o_rowp = 2624;              // NN+1
    size_t o_bed  = 102656;            // E packed bucket edges
    size_t o_col  = o_bed + (size_t)E;           // E
    size_t o_whi  = ((o_col + (size_t)E + 63) / 64) * 64;  // 73728 shorts = 36864 ints
    size_t o_wlo  = o_whi + 36864;
    size_t o_x16  = o_wlo + 36864;               // NN*32 bf16 = NN*16 ints
    size_t o_aggr = o_x16 + (size_t)NN * 16;     // NN*128 bf16 = NN*64 ints
    size_t o_hA   = o_aggr + (size_t)NN * 64;
    size_t o_hB   = o_hA + (size_t)NN * 64;

    int*    bcnt    = ws_i + o_bcnt;
    int*    bcur    = ws_i + o_bcur;
    float*  gsum    = ws_f + o_gsum;
    int*    bptr    = ws_i + o_bptr;
    int*    row_ptr = ws_i + o_rowp;
    int*    bedges  = ws_i + o_bed;
    int*    col_src = ws_i + o_col;
    short*  whi     = (short*)(ws_i + o_whi);
    short*  wlo     = (short*)(ws_i + o_wlo);
    ushort* x16     = (ushort*)(ws_i + o_x16);
    ushort* aggr    = (ushort*)(ws_i + o_aggr);
    ushort* hA      = (ushort*)(ws_i + o_hA);
    ushort* hB      = (ushort*)(ws_i + o_hB);

    short* W1l_hi = whi + 0;     short* W1l_lo = wlo + 0;
    short* W1r_hi = whi + 4096;  short* W1r_lo = wlo + 4096;
    short* W2l_hi = whi + 8192;  short* W2l_lo = wlo + 8192;
    short* W2r_hi = whi + 24576; short* W2r_lo = wlo + 24576;
    short* W3l_hi = whi + 40960; short* W3l_lo = wlo + 40960;
    short* W3r_hi = whi + 57344; short* W3r_lo = wlo + 57344;

    // zero bcnt, bcur, gsum
    hipMemsetAsync(d_ws, 0, 1792 * sizeof(int), stream);

    const int TB = 256;
    dim3 blk(TB);

    // independent prep
    to_bf16<<<(NN * 32 / 4 + TB - 1) / TB, blk, 0, stream>>>(x, x16, NN * 32);
    split_weights<<<(73728 + TB - 1) / TB, blk, 0, stream>>>(
        W1l, W1r, W2l, W2r, W3l, W3r, whi, wlo);

    // bucketed CSR build
    bucket_hist<<<256, blk, 0, stream>>>(edges, E, bcnt);
    scan_bptr<<<1, 1024, 0, stream>>>(bcnt, bptr);
    bucket_scatter<<<(E + SCAT_CHUNK - 1) / SCAT_CHUNK, blk, 0, stream>>>(
        edges, E, bptr, bcur, bedges);
    bucket_csr<<<NB, blk, 0, stream>>>(bedges, bptr, row_ptr, col_src);

    dim3 grid_a32((size_t)NN * 16 / TB);   // 6250
    dim3 grid_a128((size_t)NN * 64 / TB);  // 25000
    dim3 grid_g(512);                      // 256 row-streaming blocks per col-half

    // Layer 1 (K=32, relu)
    aggregate32_bf16<<<grid_a32, blk, 0, stream>>>(x16, row_ptr, col_src, aggr, NN);
    gemm_lds<32, true, false><<<grid_g, blk, 0, stream>>>(
        aggr, x16, W1l_hi, W1l_lo, W1r_hi, W1r_lo, b1, hA, nullptr);

    // Layer 2 (K=128, relu)
    aggregate128_bf16<<<grid_a128, blk, 0, stream>>>(hA, row_ptr, col_src, aggr, NN);
    gemm_lds<128, true, false><<<grid_g, blk, 0, stream>>>(
        aggr, hA, W2l_hi, W2l_lo, W2r_hi, W2r_lo, b2, hB, nullptr);

    // Layer 3 (K=128, fused column-mean into gsum)
    aggregate128_bf16<<<grid_a128, blk, 0, stream>>>(hB, row_ptr, col_src, aggr, NN);
    gemm_lds<128, false, true><<<grid_g, blk, 0, stream>>>(
        aggr, hB, W3l_hi, W3l_lo, W3r_hi, W3r_lo, b3, nullptr, gsum);

    // Heads (b3 folded into global mean here)
    heads_kernel<<<1, 256, 0, stream>>>(gsum, b3, Pw1, Pb1, Pw2, Pb2,
                                        Vw1, Vb1, Vw2, Vb2, outp,
                                        1.0f / (float)NN);
}